// Round 13
// baseline (84.273 us; speedup 1.0000x reference)
//
#include <hip/hip_runtime.h>
#include <hip/hip_bf16.h>
#include <math.h>

#define EPS 1e-8f

typedef __attribute__((ext_vector_type(8))) short short8;
typedef __attribute__((ext_vector_type(4))) float floatx4;
typedef unsigned short ushort_t;

#define GPTR(p) ((const __attribute__((address_space(1))) void*)(p))
#define LPTR(p) ((__attribute__((address_space(3))) void*)(p))

__device__ __forceinline__ unsigned short f2bf(float f) {
  unsigned int u = __float_as_uint(f);
  u += 0x7FFFu + ((u >> 16) & 1u);   // RNE
  return (unsigned short)(u >> 16);
}
__device__ __forceinline__ unsigned int pack2bf(float a, float b) {
  return (unsigned int)f2bf(a) | ((unsigned int)f2bf(b) << 16);
}

// ---- kA: one speaker per block. x -> x_bf, row norms (xx, rxn),
//          column sums -> sums_bf, ss, rcn. Single 96MB pass over x.
__global__ __launch_bounds__(256) void kA(const float* __restrict__ x,
    ushort_t* __restrict__ xbf, ushort_t* __restrict__ sums_bf,
    float* __restrict__ ss, float* __restrict__ rcn,
    float* __restrict__ xx, float* __restrict__ rxn,
    const float* __restrict__ wp) {
  const int n = blockIdx.x;
  const int t = threadIdx.x;
  const int wv = t >> 6, l = t & 63;
  __shared__ float csum[4][768];   // 12 KB
  float4 cs0 = {0,0,0,0}, cs1 = {0,0,0,0}, cs2 = {0,0,0,0};

  for (int r = 0; r < 16; ++r) {
    const int row = wv * 16 + r;
    const size_t base = ((size_t)n * 64 + row) * 768;
    const float* rp = x + base;
    float4 v0 = *(const float4*)(rp + l * 4);
    float4 v1 = *(const float4*)(rp + l * 4 + 256);
    float4 v2 = *(const float4*)(rp + l * 4 + 512);
    uint2 b0 = { pack2bf(v0.x, v0.y), pack2bf(v0.z, v0.w) };
    uint2 b1 = { pack2bf(v1.x, v1.y), pack2bf(v1.z, v1.w) };
    uint2 b2 = { pack2bf(v2.x, v2.y), pack2bf(v2.z, v2.w) };
    *(uint2*)(xbf + base + l * 4)       = b0;
    *(uint2*)(xbf + base + l * 4 + 256) = b1;
    *(uint2*)(xbf + base + l * 4 + 512) = b2;
    float rq = v0.x*v0.x + v0.y*v0.y + v0.z*v0.z + v0.w*v0.w
             + v1.x*v1.x + v1.y*v1.y + v1.z*v1.z + v1.w*v1.w
             + v2.x*v2.x + v2.y*v2.y + v2.z*v2.z + v2.w*v2.w;
    for (int o = 32; o; o >>= 1) rq += __shfl_xor(rq, o, 64);
    if (l == 0) {
      const int j = n * 64 + row;
      xx[j] = rq;
      rxn[j] = 1.0f / fmaxf(sqrtf(rq), EPS);
    }
    cs0.x += v0.x; cs0.y += v0.y; cs0.z += v0.z; cs0.w += v0.w;
    cs1.x += v1.x; cs1.y += v1.y; cs1.z += v1.z; cs1.w += v1.w;
    cs2.x += v2.x; cs2.y += v2.y; cs2.z += v2.z; cs2.w += v2.w;
  }
  *(float4*)&csum[wv][l * 4]       = cs0;
  *(float4*)&csum[wv][l * 4 + 256] = cs1;
  *(float4*)&csum[wv][l * 4 + 512] = cs2;
  __syncthreads();

  float lss = 0.f;
#pragma unroll
  for (int q = 0; q < 3; ++q) {
    const int c = t + q * 256;
    const float s = csum[0][c] + csum[1][c] + csum[2][c] + csum[3][c];
    sums_bf[(size_t)n * 768 + c] = f2bf(s);
    lss += s * s;
  }
  for (int o = 32; o; o >>= 1) lss += __shfl_xor(lss, o, 64);
  __syncthreads();
  if (l == 0) csum[1][wv] = lss;   // reuse LDS slot
  __syncthreads();
  if (t == 0) {
    const float v = csum[1][0] + csum[1][1] + csum[1][2] + csum[1][3];
    ss[n] = v;
    rcn[n] = (*wp) / fmaxf(sqrtf(v), 64.f * EPS);   // w / (M * cn)
  }
}

// ---- kC v6: 256n x 256j tile, 256 blocks (1/CU), 8 waves of 128n x 64j.
// A (sums_bf) via LDS: frag-major, 4 x 16KB buffers, 3-deep, counted vmcnt.
// B (x_bf) DIRECT to registers (per-wave private, no LDS), ping-pong
// prefetched 1 step ahead. LDS pipe now carries A only (~896 cyc/step).
__global__ __launch_bounds__(512, 2) void kC(const ushort_t* __restrict__ xbf,
    const ushort_t* __restrict__ sums_bf, const float* __restrict__ rcn,
    const float* __restrict__ rxn, float* __restrict__ colsum,
    float* __restrict__ sdiag_dot, const float* __restrict__ bp) {
  __shared__ ushort_t lds[4][8192];    // 4 x 16KB A buffers (16 frags each)
  const int b = blockIdx.x;
  const int xcd = b & 7;
  const int inner = b >> 3;            // 0..31
  const int nt = inner & 1;            // n-tile twins of a j-tile share an XCD
  const int jt = xcd + ((inner >> 1) << 3);   // 0..127
  const int n0 = nt * 256, j0 = jt * 256;
  const int t = threadIdx.x, wv = t >> 6, l = t & 63;
  const int wm = wv >> 2, wj = wv & 3; // 2(m) x 4(j) wave grid; wave = 128n x 64j

  // B base for this thread: row j0 + wj*64 + (l&15) (+16 per ni), k-group (l>>4)*8
  const ushort_t* Bbase = xbf + (size_t)(j0 + wj * 64 + (l & 15)) * 768 + (l >> 4) * 8;

// stage A for K-step KS_ into buffer BUF_: 2 gload_lds per thread
#define STAGE_A(KS_, BUF_) {                                                   \
    const ushort_t* As_ = sums_bf + (size_t)(n0 + wv * 16 + (l & 15)) * 768 +  \
                          (KS_) * 32 + (l >> 4) * 8;                           \
    __builtin_amdgcn_global_load_lds(GPTR(As_),                                \
        LPTR(&lds[BUF_][wv * 512]), 16, 0, 0);                                 \
    __builtin_amdgcn_global_load_lds(GPTR(As_ + (size_t)128 * 768),            \
        LPTR(&lds[BUF_][(wv + 8) * 512]), 16, 0, 0);                           \
  }

// load B frags for K-step KS_ into DST_ (4 x short8, per-wave private)
#define BLOAD(KS_, DST_) {                                                     \
    const ushort_t* Bs_ = Bbase + (KS_) * 32;                                  \
    DST_[0] = *(const short8*)(Bs_);                                           \
    DST_[1] = *(const short8*)(Bs_ + (size_t)16 * 768);                        \
    DST_[2] = *(const short8*)(Bs_ + (size_t)32 * 768);                        \
    DST_[3] = *(const short8*)(Bs_ + (size_t)48 * 768);                        \
  }

// one K-step: wait A(KB_) landed, barrier, prefetch B(KB_+1) + stage A(KB_+3),
// read af from LDS, 32 MFMA with CUR_ B-frags.
#define STEP(KB_, CUR_, NXT_) {                                                \
    if ((KB_) < 22) { asm volatile("s_waitcnt vmcnt(12)" ::: "memory"); }      \
    else            { asm volatile("s_waitcnt vmcnt(0)" ::: "memory"); }       \
    __builtin_amdgcn_s_barrier();                                              \
    __builtin_amdgcn_sched_barrier(0);                                         \
    if ((KB_) + 1 < 24) BLOAD((KB_) + 1, NXT_)                                 \
    const int cb_ = (KB_) & 3;                                                 \
    short8 af_[8];                                                             \
    _Pragma("unroll")                                                          \
    for (int mi = 0; mi < 8; ++mi)                                             \
      af_[mi] = *(const short8*)&lds[cb_][(wm * 8 + mi) * 512 + l * 8];        \
    if ((KB_) + 3 < 24) STAGE_A((KB_) + 3, ((KB_) + 3) & 3)                    \
    __builtin_amdgcn_s_setprio(1);                                             \
    _Pragma("unroll")                                                          \
    for (int mi = 0; mi < 8; ++mi)                                             \
      _Pragma("unroll")                                                        \
      for (int ni = 0; ni < 4; ++ni)                                           \
        acc[mi][ni] = __builtin_amdgcn_mfma_f32_16x16x32_bf16(                 \
            af_[mi], CUR_[ni], acc[mi][ni], 0, 0, 0);                          \
    __builtin_amdgcn_s_setprio(0);                                             \
  }

  floatx4 acc[8][4];
#pragma unroll
  for (int mi = 0; mi < 8; ++mi)
#pragma unroll
    for (int ni = 0; ni < 4; ++ni) acc[mi][ni] = (floatx4){0.f, 0.f, 0.f, 0.f};

  short8 bfA[4], bfB[4];
  STAGE_A(0, 0)
  STAGE_A(1, 1)
  STAGE_A(2, 2)
  BLOAD(0, bfA)

  for (int kb = 0; kb < 24; kb += 2) {
    STEP(kb,     bfA, bfB)
    STEP(kb + 1, bfB, bfA)
  }

  // ---- epilogue: S = acc * rcn[n] * rxn[j] + b ; colsum += exp(S); diag sx.
  const float bb = *bp;
  float rxv[4], p[4] = {0.f, 0.f, 0.f, 0.f};
#pragma unroll
  for (int ni = 0; ni < 4; ++ni)
    rxv[ni] = rxn[j0 + wj * 64 + ni * 16 + (l & 15)];
  const bool diagblk = (nt == (jt >> 6));

#pragma unroll
  for (int mi = 0; mi < 8; ++mi) {
    float4 rr = *(const float4*)&rcn[n0 + wm * 128 + mi * 16 + ((l >> 4) << 2)];
    const float rc[4] = {rr.x, rr.y, rr.z, rr.w};
#pragma unroll
    for (int ni = 0; ni < 4; ++ni) {
      floatx4 a = acc[mi][ni];
#pragma unroll
      for (int q = 0; q < 4; ++q)
        p[ni] += __expf(a[q] * rc[q] * rxv[ni] + bb);
      if (diagblk) {
        const int jg = j0 + wj * 64 + ni * 16 + (l & 15);
#pragma unroll
        for (int q = 0; q < 4; ++q) {
          const int mg = n0 + wm * 128 + mi * 16 + ((l >> 4) << 2) + q;
          if (mg == (jg >> 6)) sdiag_dot[jg] = a[q];
        }
      }
    }
  }
#pragma unroll
  for (int ni = 0; ni < 4; ++ni) {
    p[ni] += __shfl_xor(p[ni], 16, 64);
    p[ni] += __shfl_xor(p[ni], 32, 64);
  }
  if (l < 16) {
#pragma unroll
    for (int ni = 0; ni < 4; ++ni)
      atomicAdd(&colsum[j0 + wj * 64 + ni * 16 + l], p[ni]);
  }
}

// ---- kD: per-sample loss from colsum + diagonal dot, reduce to scalar -----
__global__ __launch_bounds__(256) void kD(const float* __restrict__ colsum,
    const float* __restrict__ sdiag_dot, const float* __restrict__ xx,
    const float* __restrict__ ss, const float* __restrict__ rcn,
    const float* __restrict__ wp, const float* __restrict__ bp,
    float* __restrict__ out) {
  const int j = blockIdx.x * 256 + threadIdx.x;
  const int i = j >> 6;
  const float ww = *wp, bb = *bp;
  const float sx = sdiag_dot[j];
  const float xxv = xx[j];
  const float xn = fmaxf(sqrtf(xxv), EPS);
  const float rx = 1.0f / xn;
  const float sd = sx * rcn[i] * rx + bb;                         // S_diag
  const float exn = sqrtf(fmaxf(ss[i] - 2.f * sx + xxv, 0.f)) * (1.f / 63.f);
  const float edot = (sx - xxv) * (1.f / 63.f);
  const float sm = ww * edot / (fmaxf(exn, EPS) * xn) + bb;       // S_same
  const float tot = colsum[j] - __expf(sd) + __expf(sm);
  float L = -sm + logf(fmaxf(tot, 1e-30f));
  for (int o = 32; o; o >>= 1) L += __shfl_xor(L, o, 64);
  __shared__ float red[4];
  if ((threadIdx.x & 63) == 0) red[threadIdx.x >> 6] = L;
  __syncthreads();
  if (threadIdx.x == 0) atomicAdd(out, red[0] + red[1] + red[2] + red[3]);
}

extern "C" void kernel_launch(void* const* d_in, const int* in_sizes, int n_in,
                              void* d_out, int out_size, void* d_ws, size_t ws_size,
                              hipStream_t stream) {
  const float* x  = (const float*)d_in[0];
  const float* wp = (const float*)d_in[1];
  const float* bp = (const float*)d_in[2];
  float* out = (float*)d_out;

  // ws layout (float offsets):
  float* fws = (float*)d_ws;
  float* ss        = fws;             // 512
  float* rcn       = fws + 512;       // 512
  float* xx        = fws + 1024;      // 32768
  float* rxn       = fws + 33792;     // 32768
  float* colsum    = fws + 66560;     // 32768
  float* sdiag_dot = fws + 99328;     // 32768
  ushort_t* sums_bf = (ushort_t*)(fws + 132096);   // 393216 ushorts
  ushort_t* xbf     = (ushort_t*)(fws + 328704);   // 25165824 ushorts
  // total = 12911616 floats ~= 49.3 MiB

  hipMemsetAsync(colsum, 0, 32768 * sizeof(float), stream);
  hipMemsetAsync(out, 0, sizeof(float), stream);

  kA<<<512, 256, 0, stream>>>(x, xbf, sums_bf, ss, rcn, xx, rxn, wp);
  kC<<<256, 512, 0, stream>>>(xbf, sums_bf, rcn, rxn, colsum, sdiag_dot, bp);
  kD<<<128, 256, 0, stream>>>(colsum, sdiag_dot, xx, ss, rcn, wp, bp, out);
}

// Round 14
// 73.311 us; speedup vs baseline: 1.1495x; 1.1495x over previous
//
#include <hip/hip_runtime.h>
#include <hip/hip_bf16.h>
#include <math.h>

#define EPS 1e-8f

typedef __attribute__((ext_vector_type(2))) unsigned long ulongx2;
typedef __attribute__((ext_vector_type(4))) float floatx4;
typedef unsigned short ushort_t;
typedef unsigned char uchar_t;

#define GPTR(p) ((const __attribute__((address_space(1))) void*)(p))
#define LPTR(p) ((__attribute__((address_space(3))) void*)(p))

__device__ __forceinline__ unsigned int pk4(float a, float b, float c, float d) {
  int v = __builtin_amdgcn_cvt_pk_fp8_f32(a, b, 0, false);
  v = __builtin_amdgcn_cvt_pk_fp8_f32(c, d, v, true);
  return (unsigned int)v;
}

// ---- kA: one speaker per block, 2 passes over its L2-resident 192KB.
// pass1: col sums + row norms + fp8 convert into LDS.  (HBM read of x)
// then:  sums reduce -> sums_f32, ss, rcn; fm-layout fp8 write of x.
// pass2: exact fp32 sx = dot(sums, x_j) per row -> sdiag_dot. (L2 re-read)
__global__ __launch_bounds__(256) void kA(const float* __restrict__ x,
    uchar_t* __restrict__ xbf8fm, float* __restrict__ sums_f32,
    float* __restrict__ ss, float* __restrict__ rcn,
    float* __restrict__ xx, float* __restrict__ rxn,
    float* __restrict__ sdiag_dot, const float* __restrict__ wp) {
  const int n = blockIdx.x;
  const int t = threadIdx.x;
  const int wv = t >> 6, l = t & 63;
  __shared__ uchar_t xs[4][16][768];   // 48KB fp8 staging
  __shared__ float csum[4][768];       // 12KB
  __shared__ float sums_l[768];        // 3KB
  float4 cs0 = {0,0,0,0}, cs1 = {0,0,0,0}, cs2 = {0,0,0,0};

  for (int r = 0; r < 16; ++r) {
    const int row = wv * 16 + r;
    const size_t base = ((size_t)n * 64 + row) * 768;
    const float* rp = x + base;
    float4 v0 = *(const float4*)(rp + l * 4);
    float4 v1 = *(const float4*)(rp + l * 4 + 256);
    float4 v2 = *(const float4*)(rp + l * 4 + 512);
    *(unsigned int*)&xs[wv][r][l * 4]       = pk4(v0.x, v0.y, v0.z, v0.w);
    *(unsigned int*)&xs[wv][r][l * 4 + 256] = pk4(v1.x, v1.y, v1.z, v1.w);
    *(unsigned int*)&xs[wv][r][l * 4 + 512] = pk4(v2.x, v2.y, v2.z, v2.w);
    float rq = v0.x*v0.x + v0.y*v0.y + v0.z*v0.z + v0.w*v0.w
             + v1.x*v1.x + v1.y*v1.y + v1.z*v1.z + v1.w*v1.w
             + v2.x*v2.x + v2.y*v2.y + v2.z*v2.z + v2.w*v2.w;
    for (int o = 32; o; o >>= 1) rq += __shfl_xor(rq, o, 64);
    if (l == 0) {
      const int j = n * 64 + row;
      xx[j] = rq;
      rxn[j] = 1.0f / fmaxf(sqrtf(rq), EPS);
    }
    cs0.x += v0.x; cs0.y += v0.y; cs0.z += v0.z; cs0.w += v0.w;
    cs1.x += v1.x; cs1.y += v1.y; cs1.z += v1.z; cs1.w += v1.w;
    cs2.x += v2.x; cs2.y += v2.y; cs2.z += v2.z; cs2.w += v2.w;
  }
  *(float4*)&csum[wv][l * 4]       = cs0;
  *(float4*)&csum[wv][l * 4 + 256] = cs1;
  *(float4*)&csum[wv][l * 4 + 512] = cs2;
  __syncthreads();

  float lss = 0.f;
#pragma unroll
  for (int q = 0; q < 3; ++q) {
    const int c = t + q * 256;
    const float s = csum[0][c] + csum[1][c] + csum[2][c] + csum[3][c];
    sums_l[c] = s;
    sums_f32[(size_t)n * 768 + c] = s;
    lss += s * s;
  }
  for (int o = 32; o; o >>= 1) lss += __shfl_xor(lss, o, 64);
  __syncthreads();
  if (l == 0) csum[1][wv] = lss;
  __syncthreads();
  if (t == 0) {
    const float v = csum[1][0] + csum[1][1] + csum[1][2] + csum[1][3];
    ss[n] = v;
    rcn[n] = (*wp) / fmaxf(sqrtf(v), 64.f * EPS);   // w / (M * cn)
  }

  // ---- fm-layout fp8 write: group g = n*4 + wv, 12 K64-steps, 1KB blobs
  {
    const int g = n * 4 + wv;
#pragma unroll
    for (int ks = 0; ks < 12; ++ks) {
      const uchar_t* sp = &xs[wv][l & 15][ks * 64 + (l >> 4) * 8];
      uint2 lo = *(const uint2*)sp;
      uint2 hi = *(const uint2*)(sp + 32);
      uint4 outv = {lo.x, lo.y, hi.x, hi.y};
      *(uint4*)(xbf8fm + (size_t)((g * 12 + ks) * 64 + l) * 16) = outv;
    }
  }

  // ---- pass2: exact sx per row (x re-read from L2; sums from LDS)
  for (int r = 0; r < 16; ++r) {
    const int row = wv * 16 + r;
    const size_t base = ((size_t)n * 64 + row) * 768;
    const float* rp = x + base;
    float4 v0 = *(const float4*)(rp + l * 4);
    float4 v1 = *(const float4*)(rp + l * 4 + 256);
    float4 v2 = *(const float4*)(rp + l * 4 + 512);
    float4 s0 = *(const float4*)&sums_l[l * 4];
    float4 s1 = *(const float4*)&sums_l[l * 4 + 256];
    float4 s2 = *(const float4*)&sums_l[l * 4 + 512];
    float sx = v0.x*s0.x + v0.y*s0.y + v0.z*s0.z + v0.w*s0.w
             + v1.x*s1.x + v1.y*s1.y + v1.z*s1.z + v1.w*s1.w
             + v2.x*s2.x + v2.y*s2.y + v2.z*s2.z + v2.w*s2.w;
    for (int o = 32; o; o >>= 1) sx += __shfl_xor(sx, o, 64);
    if (l == 0) sdiag_dot[n * 64 + row] = sx;
  }
}

// ---- kA2: sums_f32 -> fp8 fm layout (32 groups x 12 ks x 1KB). Tiny.
__global__ __launch_bounds__(256) void kA2(const float* __restrict__ sums_f32,
    uchar_t* __restrict__ sums8fm) {
  const int g = blockIdx.x;
  const int wv = threadIdx.x >> 6, l = threadIdx.x & 63;
#pragma unroll
  for (int ksi = 0; ksi < 3; ++ksi) {
    const int ks = wv * 3 + ksi;
    const float* sp = sums_f32 + (size_t)(g * 16 + (l & 15)) * 768
                      + ks * 64 + (l >> 4) * 8;
    float4 a0 = *(const float4*)sp;
    float4 a1 = *(const float4*)(sp + 4);
    float4 b0 = *(const float4*)(sp + 32);
    float4 b1 = *(const float4*)(sp + 36);
    uint4 outv = { pk4(a0.x, a0.y, a0.z, a0.w), pk4(a1.x, a1.y, a1.z, a1.w),
                   pk4(b0.x, b0.y, b0.z, b0.w), pk4(b1.x, b1.y, b1.z, b1.w) };
    *(uint4*)(sums8fm + (size_t)((g * 12 + ks) * 64 + l) * 16) = outv;
  }
}

// ---- kC v7: fp8 GEMM, 256n x 256j tile, 256 blocks (1/CU), 8 waves.
// Operands in fm layout -> gload_lds reads contiguous 1KB blobs (L2-linear,
// xbf8 working set fits L2). 12 K64-steps, 4 x 32KB buffers, counted vmcnt.
__global__ __launch_bounds__(512, 2) void kC(const uchar_t* __restrict__ xbf8fm,
    const uchar_t* __restrict__ sums8fm, const float* __restrict__ rcn,
    const float* __restrict__ rxn, float* __restrict__ colsum,
    const float* __restrict__ bp) {
  __shared__ uchar_t lds[4][32768];    // [A blobs 0..15 | B blobs 0..15] x 1KB
  const int b = blockIdx.x;
  const int xcd = b & 7;
  const int inner = b >> 3;
  const int nt = inner & 1;
  const int jt = xcd + ((inner >> 1) << 3);
  const int n0 = nt * 256, j0 = jt * 256;
  const int t = threadIdx.x, wv = t >> 6, l = t & 63;
  const int wm = wv >> 2, wj = wv & 3;
  const int gA0 = n0 / 16, gB0 = j0 / 16;

#define STAGE(KS_, BUF_) {                                                     \
    const int fb0_ = wv * 2, fb1_ = wv * 2 + 1;                                \
    __builtin_amdgcn_global_load_lds(                                          \
        GPTR(sums8fm + (size_t)(((gA0 + fb0_) * 12 + (KS_)) * 64 + l) * 16),   \
        LPTR(&lds[BUF_][fb0_ * 1024]), 16, 0, 0);                              \
    __builtin_amdgcn_global_load_lds(                                          \
        GPTR(sums8fm + (size_t)(((gA0 + fb1_) * 12 + (KS_)) * 64 + l) * 16),   \
        LPTR(&lds[BUF_][fb1_ * 1024]), 16, 0, 0);                              \
    __builtin_amdgcn_global_load_lds(                                          \
        GPTR(xbf8fm + (size_t)(((gB0 + fb0_) * 12 + (KS_)) * 64 + l) * 16),    \
        LPTR(&lds[BUF_][16384 + fb0_ * 1024]), 16, 0, 0);                      \
    __builtin_amdgcn_global_load_lds(                                          \
        GPTR(xbf8fm + (size_t)(((gB0 + fb1_) * 12 + (KS_)) * 64 + l) * 16),    \
        LPTR(&lds[BUF_][16384 + fb1_ * 1024]), 16, 0, 0);                      \
  }

  floatx4 acc[8][4];
#pragma unroll
  for (int mi = 0; mi < 8; ++mi)
#pragma unroll
    for (int ni = 0; ni < 4; ++ni) acc[mi][ni] = (floatx4){0.f, 0.f, 0.f, 0.f};

  STAGE(0, 0)
  STAGE(1, 1)
  STAGE(2, 2)                          // 12 loads/thread outstanding

  for (int kb = 0; kb < 12; ++kb) {
    if (kb < 10)       { asm volatile("s_waitcnt vmcnt(8)" ::: "memory"); }
    else if (kb == 10) { asm volatile("s_waitcnt vmcnt(4)" ::: "memory"); }
    else               { asm volatile("s_waitcnt vmcnt(0)" ::: "memory"); }
    __builtin_amdgcn_s_barrier();
    __builtin_amdgcn_sched_barrier(0);   // keep ds_reads below the barrier
    const int cb = kb & 3, sb = (kb + 3) & 3;

    ulongx2 af[8], bf[4];
#pragma unroll
    for (int ni = 0; ni < 4; ++ni)
      bf[ni] = *(const ulongx2*)&lds[cb][16384 + (wj * 4 + ni) * 1024 + l * 16];
#pragma unroll
    for (int mi = 0; mi < 8; ++mi)
      af[mi] = *(const ulongx2*)&lds[cb][(wm * 8 + mi) * 1024 + l * 16];
    if (kb + 3 < 12) STAGE(kb + 3, sb)
    __builtin_amdgcn_s_setprio(1);
#pragma unroll
    for (int mi = 0; mi < 8; ++mi)
#pragma unroll
      for (int ni = 0; ni < 4; ++ni) {
        acc[mi][ni] = __builtin_amdgcn_mfma_f32_16x16x32_fp8_fp8(
            (long)af[mi].x, (long)bf[ni].x, acc[mi][ni], 0, 0, 0);
        acc[mi][ni] = __builtin_amdgcn_mfma_f32_16x16x32_fp8_fp8(
            (long)af[mi].y, (long)bf[ni].y, acc[mi][ni], 0, 0, 0);
      }
    __builtin_amdgcn_s_setprio(0);
  }

  // ---- epilogue: S = acc * rcn[n] * rxn[j] + b ; colsum += exp(S).
  const float bb = *bp;
  float rxv[4], p[4] = {0.f, 0.f, 0.f, 0.f};
#pragma unroll
  for (int ni = 0; ni < 4; ++ni)
    rxv[ni] = rxn[j0 + wj * 64 + ni * 16 + (l & 15)];

#pragma unroll
  for (int mi = 0; mi < 8; ++mi) {
    float4 rr = *(const float4*)&rcn[n0 + wm * 128 + mi * 16 + ((l >> 4) << 2)];
    const float rc[4] = {rr.x, rr.y, rr.z, rr.w};
#pragma unroll
    for (int ni = 0; ni < 4; ++ni) {
      floatx4 a = acc[mi][ni];
#pragma unroll
      for (int q = 0; q < 4; ++q)
        p[ni] += __expf(a[q] * rc[q] * rxv[ni] + bb);
    }
  }
#pragma unroll
  for (int ni = 0; ni < 4; ++ni) {
    p[ni] += __shfl_xor(p[ni], 16, 64);
    p[ni] += __shfl_xor(p[ni], 32, 64);
  }
  if (l < 16) {
#pragma unroll
    for (int ni = 0; ni < 4; ++ni)
      atomicAdd(&colsum[j0 + wj * 64 + ni * 16 + l], p[ni]);
  }
}

// ---- kD: per-sample loss from colsum + exact diagonal dot ----------------
__global__ __launch_bounds__(256) void kD(const float* __restrict__ colsum,
    const float* __restrict__ sdiag_dot, const float* __restrict__ xx,
    const float* __restrict__ ss, const float* __restrict__ rcn,
    const float* __restrict__ wp, const float* __restrict__ bp,
    float* __restrict__ out) {
  const int j = blockIdx.x * 256 + threadIdx.x;
  const int i = j >> 6;
  const float ww = *wp, bb = *bp;
  const float sx = sdiag_dot[j];
  const float xxv = xx[j];
  const float xn = fmaxf(sqrtf(xxv), EPS);
  const float rx = 1.0f / xn;
  const float sd = sx * rcn[i] * rx + bb;                         // S_diag
  const float exn = sqrtf(fmaxf(ss[i] - 2.f * sx + xxv, 0.f)) * (1.f / 63.f);
  const float edot = (sx - xxv) * (1.f / 63.f);
  const float sm = ww * edot / (fmaxf(exn, EPS) * xn) + bb;       // S_same
  const float tot = colsum[j] - __expf(sd) + __expf(sm);
  float L = -sm + logf(fmaxf(tot, 1e-30f));
  for (int o = 32; o; o >>= 1) L += __shfl_xor(L, o, 64);
  __shared__ float red[4];
  if ((threadIdx.x & 63) == 0) red[threadIdx.x >> 6] = L;
  __syncthreads();
  if (threadIdx.x == 0) atomicAdd(out, red[0] + red[1] + red[2] + red[3]);
}

extern "C" void kernel_launch(void* const* d_in, const int* in_sizes, int n_in,
                              void* d_out, int out_size, void* d_ws, size_t ws_size,
                              hipStream_t stream) {
  const float* x  = (const float*)d_in[0];
  const float* wp = (const float*)d_in[1];
  const float* bp = (const float*)d_in[2];
  float* out = (float*)d_out;

  // ws layout (float offsets):
  float* fws = (float*)d_ws;
  float* ss        = fws;             // 512
  float* rcn       = fws + 512;       // 512
  float* xx        = fws + 1024;      // 32768
  float* rxn       = fws + 33792;     // 32768
  float* colsum    = fws + 66560;     // 32768
  float* sdiag_dot = fws + 99328;     // 32768
  float* sums_f32  = fws + 132096;    // 393216
  uchar_t* sums8fm = (uchar_t*)(fws + 525312);   // 393216 bytes = 98304 floats
  uchar_t* xbf8fm  = (uchar_t*)(fws + 623616);   // 25165824 bytes = 6291456 floats
  // total = 6915072 floats ~= 27.7 MiB

  hipMemsetAsync(colsum, 0, 32768 * sizeof(float), stream);
  hipMemsetAsync(out, 0, sizeof(float), stream);

  kA<<<512, 256, 0, stream>>>(x, xbf8fm, sums_f32, ss, rcn, xx, rxn, sdiag_dot, wp);
  kA2<<<32, 256, 0, stream>>>(sums_f32, sums8fm);
  kC<<<256, 512, 0, stream>>>(xbf8fm, sums8fm, rcn, rxn, colsum, bp);
  kD<<<128, 256, 0, stream>>>(colsum, sdiag_dot, xx, ss, rcn, wp, bp, out);
}

// Round 15
// 58.378 us; speedup vs baseline: 1.4436x; 1.2558x over previous
//
#include <hip/hip_runtime.h>
#include <hip/hip_bf16.h>
#include <math.h>

#define EPS 1e-8f

typedef __attribute__((ext_vector_type(2))) unsigned long ulongx2;
typedef __attribute__((ext_vector_type(4))) float floatx4;
typedef unsigned char uchar_t;

#define GPTR(p) ((const __attribute__((address_space(1))) void*)(p))
#define LPTR(p) ((__attribute__((address_space(3))) void*)(p))

__device__ __forceinline__ unsigned int pk4(float a, float b, float c, float d) {
  int v = __builtin_amdgcn_cvt_pk_fp8_f32(a, b, 0, false);
  v = __builtin_amdgcn_cvt_pk_fp8_f32(c, d, v, true);
  return (unsigned int)v;
}

// ---- kA: one speaker per block, SINGLE pass over x.
// col sums -> sums_f32/ss/rcn; row norms -> xx/rxn; fp8 convert staged in
// padded LDS (stride 776B: 194 dw === 2 mod 32 -> ~2-way, free) then written
// out in fm layout (1KB blobs per (group, K64-step)).
__global__ __launch_bounds__(256) void kA(const float* __restrict__ x,
    uchar_t* __restrict__ xbf8fm, float* __restrict__ sums_f32,
    float* __restrict__ ss, float* __restrict__ rcn,
    float* __restrict__ xx, float* __restrict__ rxn,
    const float* __restrict__ wp) {
  const int n = blockIdx.x;
  const int t = threadIdx.x;
  const int wv = t >> 6, l = t & 63;
  __shared__ uchar_t xs[4][16][776];   // ~49.7KB padded fp8 staging
  __shared__ float csum[4][768];       // 12KB
  float4 cs0 = {0,0,0,0}, cs1 = {0,0,0,0}, cs2 = {0,0,0,0};

  for (int r = 0; r < 16; ++r) {
    const int row = wv * 16 + r;
    const size_t base = ((size_t)n * 64 + row) * 768;
    const float* rp = x + base;
    float4 v0 = *(const float4*)(rp + l * 4);
    float4 v1 = *(const float4*)(rp + l * 4 + 256);
    float4 v2 = *(const float4*)(rp + l * 4 + 512);
    *(unsigned int*)&xs[wv][r][l * 4]       = pk4(v0.x, v0.y, v0.z, v0.w);
    *(unsigned int*)&xs[wv][r][l * 4 + 256] = pk4(v1.x, v1.y, v1.z, v1.w);
    *(unsigned int*)&xs[wv][r][l * 4 + 512] = pk4(v2.x, v2.y, v2.z, v2.w);
    float rq = v0.x*v0.x + v0.y*v0.y + v0.z*v0.z + v0.w*v0.w
             + v1.x*v1.x + v1.y*v1.y + v1.z*v1.z + v1.w*v1.w
             + v2.x*v2.x + v2.y*v2.y + v2.z*v2.z + v2.w*v2.w;
    for (int o = 32; o; o >>= 1) rq += __shfl_xor(rq, o, 64);
    if (l == 0) {
      const int j = n * 64 + row;
      xx[j] = rq;
      rxn[j] = 1.0f / fmaxf(sqrtf(rq), EPS);
    }
    cs0.x += v0.x; cs0.y += v0.y; cs0.z += v0.z; cs0.w += v0.w;
    cs1.x += v1.x; cs1.y += v1.y; cs1.z += v1.z; cs1.w += v1.w;
    cs2.x += v2.x; cs2.y += v2.y; cs2.z += v2.z; cs2.w += v2.w;
  }
  *(float4*)&csum[wv][l * 4]       = cs0;
  *(float4*)&csum[wv][l * 4 + 256] = cs1;
  *(float4*)&csum[wv][l * 4 + 512] = cs2;
  __syncthreads();

  float lss = 0.f;
#pragma unroll
  for (int q = 0; q < 3; ++q) {
    const int c = t + q * 256;
    const float s = csum[0][c] + csum[1][c] + csum[2][c] + csum[3][c];
    sums_f32[(size_t)n * 768 + c] = s;
    lss += s * s;
  }
  for (int o = 32; o; o >>= 1) lss += __shfl_xor(lss, o, 64);
  __syncthreads();
  if (l == 0) csum[1][wv] = lss;
  __syncthreads();
  if (t == 0) {
    const float v = csum[1][0] + csum[1][1] + csum[1][2] + csum[1][3];
    ss[n] = v;
    rcn[n] = (*wp) / fmaxf(sqrtf(v), 64.f * EPS);   // w / (M * cn)
  }

  // ---- fm-layout fp8 write: group g = n*4 + wv, 12 K64-steps, 1KB blobs
  {
    const int g = n * 4 + wv;
#pragma unroll
    for (int ks = 0; ks < 12; ++ks) {
      const uchar_t* sp = &xs[wv][l & 15][ks * 64 + (l >> 4) * 8];
      uint2 lo = *(const uint2*)sp;
      uint2 hi = *(const uint2*)(sp + 32);
      uint4 outv = {lo.x, lo.y, hi.x, hi.y};
      *(uint4*)(xbf8fm + (size_t)((g * 12 + ks) * 64 + l) * 16) = outv;
    }
  }
}

// ---- kA2: sums_f32 -> fp8 fm layout (32 groups x 12 ks x 1KB). Tiny.
__global__ __launch_bounds__(256) void kA2(const float* __restrict__ sums_f32,
    uchar_t* __restrict__ sums8fm) {
  const int g = blockIdx.x;
  const int wv = threadIdx.x >> 6, l = threadIdx.x & 63;
#pragma unroll
  for (int ksi = 0; ksi < 3; ++ksi) {
    const int ks = wv * 3 + ksi;
    const float* sp = sums_f32 + (size_t)(g * 16 + (l & 15)) * 768
                      + ks * 64 + (l >> 4) * 8;
    float4 a0 = *(const float4*)sp;
    float4 a1 = *(const float4*)(sp + 4);
    float4 b0 = *(const float4*)(sp + 32);
    float4 b1 = *(const float4*)(sp + 36);
    uint4 outv = { pk4(a0.x, a0.y, a0.z, a0.w), pk4(a1.x, a1.y, a1.z, a1.w),
                   pk4(b0.x, b0.y, b0.z, b0.w), pk4(b1.x, b1.y, b1.z, b1.w) };
    *(uint4*)(sums8fm + (size_t)((g * 12 + ks) * 64 + l) * 16) = outv;
  }
}

// ---- kC: fp8 GEMM, 256n x 256j tile, 256 blocks (1/CU), 8 waves.
// fm-layout operands -> gload_lds reads contiguous 1KB blobs (L2-linear).
// 12 K64-steps, 4 x 32KB buffers, counted vmcnt. Fused epilogue:
// exp + colsum atomics + diagonal sx extraction (consistent cancellation).
__global__ __launch_bounds__(512, 2) void kC(const uchar_t* __restrict__ xbf8fm,
    const uchar_t* __restrict__ sums8fm, const float* __restrict__ rcn,
    const float* __restrict__ rxn, float* __restrict__ colsum,
    float* __restrict__ sdiag_dot, const float* __restrict__ bp) {
  __shared__ uchar_t lds[4][32768];    // [A blobs 0..15 | B blobs 0..15] x 1KB
  const int b = blockIdx.x;
  const int xcd = b & 7;
  const int inner = b >> 3;
  const int nt = inner & 1;
  const int jt = xcd + ((inner >> 1) << 3);
  const int n0 = nt * 256, j0 = jt * 256;
  const int t = threadIdx.x, wv = t >> 6, l = t & 63;
  const int wm = wv >> 2, wj = wv & 3;
  const int gA0 = n0 / 16, gB0 = j0 / 16;

#define STAGE(KS_, BUF_) {                                                     \
    const int fb0_ = wv * 2, fb1_ = wv * 2 + 1;                                \
    __builtin_amdgcn_global_load_lds(                                          \
        GPTR(sums8fm + (size_t)(((gA0 + fb0_) * 12 + (KS_)) * 64 + l) * 16),   \
        LPTR(&lds[BUF_][fb0_ * 1024]), 16, 0, 0);                              \
    __builtin_amdgcn_global_load_lds(                                          \
        GPTR(sums8fm + (size_t)(((gA0 + fb1_) * 12 + (KS_)) * 64 + l) * 16),   \
        LPTR(&lds[BUF_][fb1_ * 1024]), 16, 0, 0);                              \
    __builtin_amdgcn_global_load_lds(                                          \
        GPTR(xbf8fm + (size_t)(((gB0 + fb0_) * 12 + (KS_)) * 64 + l) * 16),    \
        LPTR(&lds[BUF_][16384 + fb0_ * 1024]), 16, 0, 0);                      \
    __builtin_amdgcn_global_load_lds(                                          \
        GPTR(xbf8fm + (size_t)(((gB0 + fb1_) * 12 + (KS_)) * 64 + l) * 16),    \
        LPTR(&lds[BUF_][16384 + fb1_ * 1024]), 16, 0, 0);                      \
  }

  floatx4 acc[8][4];
#pragma unroll
  for (int mi = 0; mi < 8; ++mi)
#pragma unroll
    for (int ni = 0; ni < 4; ++ni) acc[mi][ni] = (floatx4){0.f, 0.f, 0.f, 0.f};

  STAGE(0, 0)
  STAGE(1, 1)
  STAGE(2, 2)                          // 12 loads/thread outstanding

  for (int kb = 0; kb < 12; ++kb) {
    if (kb < 10)       { asm volatile("s_waitcnt vmcnt(8)" ::: "memory"); }
    else if (kb == 10) { asm volatile("s_waitcnt vmcnt(4)" ::: "memory"); }
    else               { asm volatile("s_waitcnt vmcnt(0)" ::: "memory"); }
    __builtin_amdgcn_s_barrier();
    __builtin_amdgcn_sched_barrier(0);   // keep ds_reads below the barrier
    const int cb = kb & 3, sb = (kb + 3) & 3;

    ulongx2 af[8], bf[4];
#pragma unroll
    for (int ni = 0; ni < 4; ++ni)
      bf[ni] = *(const ulongx2*)&lds[cb][16384 + (wj * 4 + ni) * 1024 + l * 16];
#pragma unroll
    for (int mi = 0; mi < 8; ++mi)
      af[mi] = *(const ulongx2*)&lds[cb][(wm * 8 + mi) * 1024 + l * 16];
    if (kb + 3 < 12) STAGE(kb + 3, sb)
    __builtin_amdgcn_s_setprio(1);
#pragma unroll
    for (int mi = 0; mi < 8; ++mi)
#pragma unroll
      for (int ni = 0; ni < 4; ++ni) {
        acc[mi][ni] = __builtin_amdgcn_mfma_f32_16x16x32_fp8_fp8(
            (long)af[mi].x, (long)bf[ni].x, acc[mi][ni], 0, 0, 0);
        acc[mi][ni] = __builtin_amdgcn_mfma_f32_16x16x32_fp8_fp8(
            (long)af[mi].y, (long)bf[ni].y, acc[mi][ni], 0, 0, 0);
      }
    __builtin_amdgcn_s_setprio(0);
  }

  // ---- epilogue: S = acc * rcn[n] * rxn[j] + b ; colsum += exp(S); diag sx.
  const float bb = *bp;
  float rxv[4], p[4] = {0.f, 0.f, 0.f, 0.f};
#pragma unroll
  for (int ni = 0; ni < 4; ++ni)
    rxv[ni] = rxn[j0 + wj * 64 + ni * 16 + (l & 15)];
  const bool diagblk = (nt == (jt >> 6));

#pragma unroll
  for (int mi = 0; mi < 8; ++mi) {
    float4 rr = *(const float4*)&rcn[n0 + wm * 128 + mi * 16 + ((l >> 4) << 2)];
    const float rc[4] = {rr.x, rr.y, rr.z, rr.w};
#pragma unroll
    for (int ni = 0; ni < 4; ++ni) {
      floatx4 a = acc[mi][ni];
#pragma unroll
      for (int q = 0; q < 4; ++q)
        p[ni] += __expf(a[q] * rc[q] * rxv[ni] + bb);
      if (diagblk) {
        const int jg = j0 + wj * 64 + ni * 16 + (l & 15);
#pragma unroll
        for (int q = 0; q < 4; ++q) {
          const int mg = n0 + wm * 128 + mi * 16 + ((l >> 4) << 2) + q;
          if (mg == (jg >> 6)) sdiag_dot[jg] = a[q];
        }
      }
    }
  }
#pragma unroll
  for (int ni = 0; ni < 4; ++ni) {
    p[ni] += __shfl_xor(p[ni], 16, 64);
    p[ni] += __shfl_xor(p[ni], 32, 64);
  }
  if (l < 16) {
#pragma unroll
    for (int ni = 0; ni < 4; ++ni)
      atomicAdd(&colsum[j0 + wj * 64 + ni * 16 + l], p[ni]);
  }
}

// ---- kD: per-sample loss from colsum + diagonal dot, reduce to scalar -----
__global__ __launch_bounds__(256) void kD(const float* __restrict__ colsum,
    const float* __restrict__ sdiag_dot, const float* __restrict__ xx,
    const float* __restrict__ ss, const float* __restrict__ rcn,
    const float* __restrict__ wp, const float* __restrict__ bp,
    float* __restrict__ out) {
  const int j = blockIdx.x * 256 + threadIdx.x;
  const int i = j >> 6;
  const float ww = *wp, bb = *bp;
  const float sx = sdiag_dot[j];
  const float xxv = xx[j];
  const float xn = fmaxf(sqrtf(xxv), EPS);
  const float rx = 1.0f / xn;
  const float sd = sx * rcn[i] * rx + bb;                         // S_diag
  const float exn = sqrtf(fmaxf(ss[i] - 2.f * sx + xxv, 0.f)) * (1.f / 63.f);
  const float edot = (sx - xxv) * (1.f / 63.f);
  const float sm = ww * edot / (fmaxf(exn, EPS) * xn) + bb;       // S_same
  const float tot = colsum[j] - __expf(sd) + __expf(sm);
  float L = -sm + logf(fmaxf(tot, 1e-30f));
  for (int o = 32; o; o >>= 1) L += __shfl_xor(L, o, 64);
  __shared__ float red[4];
  if ((threadIdx.x & 63) == 0) red[threadIdx.x >> 6] = L;
  __syncthreads();
  if (threadIdx.x == 0) atomicAdd(out, red[0] + red[1] + red[2] + red[3]);
}

extern "C" void kernel_launch(void* const* d_in, const int* in_sizes, int n_in,
                              void* d_out, int out_size, void* d_ws, size_t ws_size,
                              hipStream_t stream) {
  const float* x  = (const float*)d_in[0];
  const float* wp = (const float*)d_in[1];
  const float* bp = (const float*)d_in[2];
  float* out = (float*)d_out;

  // ws layout (float offsets):
  float* fws = (float*)d_ws;
  float* ss        = fws;             // 512
  float* rcn       = fws + 512;       // 512
  float* xx        = fws + 1024;      // 32768
  float* rxn       = fws + 33792;     // 32768
  float* colsum    = fws + 66560;     // 32768
  float* sdiag_dot = fws + 99328;     // 32768
  float* sums_f32  = fws + 132096;    // 393216
  uchar_t* sums8fm = (uchar_t*)(fws + 525312);   // 393216 bytes
  uchar_t* xbf8fm  = (uchar_t*)(fws + 623616);   // 25165824 bytes
  // total ~= 27.7 MiB

  hipMemsetAsync(colsum, 0, 32768 * sizeof(float), stream);
  hipMemsetAsync(out, 0, sizeof(float), stream);

  kA<<<512, 256, 0, stream>>>(x, xbf8fm, sums_f32, ss, rcn, xx, rxn, wp);
  kA2<<<32, 256, 0, stream>>>(sums_f32, sums8fm);
  kC<<<256, 512, 0, stream>>>(xbf8fm, sums8fm, rcn, rxn, colsum, sdiag_dot, bp);
  kD<<<128, 256, 0, stream>>>(colsum, sdiag_dot, xx, ss, rcn, wp, bp, out);
}